// Round 1
// baseline (253.498 us; speedup 1.0000x reference)
//
#include <hip/hip_runtime.h>

#define N_TOK 131072
#define DIM 64
#define K_CODES 1024
#define ALPHA 0.9f

#define TM 128    // rows per block
#define TK 128    // codes per LDS chunk
#define PAD 68    // padded LDS row stride in floats (16B aligned, 2-way bank alias = free)

// ---------------- w2 precompute: ||w_k||^2 ----------------
__global__ __launch_bounds__(256) void w2_kernel(const float* __restrict__ W,
                                                 float* __restrict__ w2) {
    int k = blockIdx.x * 256 + threadIdx.x;
    if (k < K_CODES) {
        const float4* wr = (const float4*)(W + (size_t)k * DIM);
        float s = 0.f;
#pragma unroll
        for (int i = 0; i < DIM / 4; ++i) {
            float4 v = wr[i];
            s += v.x * v.x + v.y * v.y + v.z * v.z + v.w * v.w;
        }
        w2[k] = s;
    }
}

// ---------------- main fused kernel ----------------
__global__ __launch_bounds__(256, 2) void vq_kernel(const float* __restrict__ x,
                                                    const float* __restrict__ W,
                                                    const float* __restrict__ w2g,
                                                    float* __restrict__ out,
                                                    float* __restrict__ blocksum) {
    __shared__ float xs[TM * PAD];   // 34816 B
    __shared__ float ws[TK * PAD];   // 34816 B (reused as argmin scratch)
    __shared__ float w2s[TK];
    __shared__ int   jrow[TM];
    __shared__ float wavesum[4];

    const int t  = threadIdx.x;
    const int tx = t & 15;
    const int ty = t >> 4;
    const int row0 = blockIdx.x * TM;

    // ---- stage x tile: 128 rows x 64 floats ----
    {
        const float4* xg = (const float4*)(x + (size_t)row0 * DIM);
#pragma unroll
        for (int i = 0; i < 8; ++i) {
            int idx = t + i * 256;      // float4 index 0..2047
            int r = idx >> 4;           // 16 float4 per row
            int c = idx & 15;
            float4 v = xg[idx];
            *(float4*)&xs[r * PAD + c * 4] = v;
        }
    }

    // per-thread best over codes {tx + 16*j + kc}
    float best[8];
    int   bidx[8];
#pragma unroll
    for (int i = 0; i < 8; ++i) { best[i] = 3.4e38f; bidx[i] = 0x7fffffff; }

    for (int kc = 0; kc < K_CODES; kc += TK) {
        __syncthreads();   // protect ws against previous iteration readers
        // ---- stage W chunk: 128 codes x 64 floats ----
        const float4* wg = (const float4*)(W + (size_t)kc * DIM);
#pragma unroll
        for (int i = 0; i < 8; ++i) {
            int idx = t + i * 256;
            int r = idx >> 4;
            int c = idx & 15;
            float4 v = wg[idx];
            *(float4*)&ws[r * PAD + c * 4] = v;
        }
        if (t < TK) w2s[t] = w2g[kc + t];
        __syncthreads();

        // ---- 8x8 register tile dot products ----
        float dot[8][8];
#pragma unroll
        for (int i = 0; i < 8; ++i)
#pragma unroll
            for (int j = 0; j < 8; ++j) dot[i][j] = 0.f;

        for (int d = 0; d < DIM; d += 4) {
            float4 xa[8], wb[8];
#pragma unroll
            for (int i = 0; i < 8; ++i) xa[i] = *(const float4*)&xs[(ty + i * 16) * PAD + d];
#pragma unroll
            for (int j = 0; j < 8; ++j) wb[j] = *(const float4*)&ws[(tx + j * 16) * PAD + d];
#pragma unroll
            for (int i = 0; i < 8; ++i)
#pragma unroll
                for (int j = 0; j < 8; ++j) {
                    dot[i][j] += xa[i].x * wb[j].x + xa[i].y * wb[j].y +
                                 xa[i].z * wb[j].z + xa[i].w * wb[j].w;
                }
        }

        // ---- update running argmin (ascending k order; first-min tie-break) ----
#pragma unroll
        for (int i = 0; i < 8; ++i)
#pragma unroll
            for (int j = 0; j < 8; ++j) {
                int   k = kc + tx + j * 16;
                float s = w2s[tx + j * 16] - 2.f * dot[i][j];
                if (s < best[i] || (s == best[i] && k < bidx[i])) {
                    best[i] = s;
                    bidx[i] = k;
                }
            }
    }

    // ---- cross-thread argmin reduction (16 threads per row) ----
    __syncthreads();
    float* reds = ws;                    // [128][16] scores
    int*   redi = (int*)(ws + TM * 16);  // [128][16] indices
#pragma unroll
    for (int i = 0; i < 8; ++i) {
        int r = ty + i * 16;
        reds[r * 16 + tx] = best[i];
        redi[r * 16 + tx] = bidx[i];
    }
    __syncthreads();
    if (t < TM) {
        float b  = reds[t * 16];
        int   bi = redi[t * 16];
#pragma unroll
        for (int q = 1; q < 16; ++q) {
            float s  = reds[t * 16 + q];
            int   k2 = redi[t * 16 + q];
            if (s < b || (s == b && k2 < bi)) { b = s; bi = k2; }
        }
        jrow[t] = bi;
    }
    __syncthreads();

    // ---- epilogue: write W_j, accumulate loss partial ----
    float psum = 0.f;
#pragma unroll
    for (int i = 0; i < 8; ++i) {
        int idx = t + i * 256;
        int r = idx >> 4;
        int c = idx & 15;
        int j = jrow[r];
        float4 wv = *(const float4*)(W + (size_t)j * DIM + c * 4);
        *(float4*)(out + (size_t)(row0 + r) * DIM + c * 4) = wv;
        float4 xv = *(const float4*)&xs[r * PAD + c * 4];
        float dx = xv.x - wv.x, dy = xv.y - wv.y;
        float dz = xv.z - wv.z, dw = xv.w - wv.w;
        psum += dx * dx + dy * dy + dz * dz + dw * dw;
    }

    // block reduce psum
#pragma unroll
    for (int off = 32; off; off >>= 1) psum += __shfl_down(psum, off);
    if ((t & 63) == 0) wavesum[t >> 6] = psum;
    __syncthreads();
    if (t == 0) blocksum[blockIdx.x] = wavesum[0] + wavesum[1] + wavesum[2] + wavesum[3];
}

// ---------------- deterministic finish: sum block partials, scale ----------------
__global__ __launch_bounds__(256) void finish_kernel(const float* __restrict__ bs,
                                                     float* __restrict__ out) {
    __shared__ float wavesum[4];
    int t = threadIdx.x;
    float s = 0.f;
    for (int i = t; i < N_TOK / TM; i += 256) s += bs[i];
#pragma unroll
    for (int off = 32; off; off >>= 1) s += __shfl_down(s, off);
    if ((t & 63) == 0) wavesum[t >> 6] = s;
    __syncthreads();
    if (t == 0)
        out[(size_t)N_TOK * DIM] = (wavesum[0] + wavesum[1] + wavesum[2] + wavesum[3]) *
                                   ((1.0f + ALPHA) / (float)N_TOK);
}

extern "C" void kernel_launch(void* const* d_in, const int* in_sizes, int n_in,
                              void* d_out, int out_size, void* d_ws, size_t ws_size,
                              hipStream_t stream) {
    const float* x = (const float*)d_in[0];
    const float* W = (const float*)d_in[1];
    float* out = (float*)d_out;
    float* ws  = (float*)d_ws;

    float* blocksum = ws;          // N_TOK/TM = 1024 floats
    float* w2       = ws + 1024;   // K_CODES floats

    w2_kernel<<<K_CODES / 256, 256, 0, stream>>>(W, w2);
    vq_kernel<<<N_TOK / TM, 256, 0, stream>>>(x, W, w2, out, blocksum);
    finish_kernel<<<1, 256, 0, stream>>>(blocksum, out);
}

// Round 2
// 68.010 us; speedup vs baseline: 3.7274x; 3.7274x over previous
//
#include <hip/hip_runtime.h>

#define N_TOK 131072
#define DIM 64
#define K_CODES 1024
#define ALPHA 0.9f

#define TM 128              // rows per block
#define TK 128              // codes per LDS chunk
#define NCHUNK (K_CODES / TK)

typedef short bf16x8 __attribute__((ext_vector_type(8)));
typedef float f32x4  __attribute__((ext_vector_type(4)));

// float -> bf16 bits, round-to-nearest-even (no NaN in this data)
__device__ __forceinline__ short f2bf(float f) {
    unsigned u = __builtin_bit_cast(unsigned, f);
    u += 0x7fffu + ((u >> 16) & 1u);
    return (short)(u >> 16);
}

// ---------------- w2 precompute: ||w_k||^2 (fp32 exact) ----------------
__global__ __launch_bounds__(256) void w2_kernel(const float* __restrict__ W,
                                                 float* __restrict__ w2) {
    int k = blockIdx.x * 256 + threadIdx.x;
    if (k < K_CODES) {
        const float4* wr = (const float4*)(W + (size_t)k * DIM);
        float s = 0.f;
#pragma unroll
        for (int i = 0; i < DIM / 4; ++i) {
            float4 v = wr[i];
            s += v.x * v.x + v.y * v.y + v.z * v.z + v.w * v.w;
        }
        w2[k] = s;
    }
}

// ---------------- main fused MFMA kernel ----------------
__global__ __launch_bounds__(256, 4) void vq_kernel(const float* __restrict__ x,
                                                    const float* __restrict__ W,
                                                    const float* __restrict__ w2g,
                                                    float* __restrict__ out,
                                                    float* __restrict__ blocksum) {
    // LDS map:
    //  [0, 32768)      : W chunk double buffer, bf16 swizzled, 2 x 128x64
    //                    (reused at the end as argmin reduce scratch)
    //  [32768, 36864)  : w2s, 1024 fp32
    //  [36864, 37376)  : jrow, 128 int
    //  [37376, 37392)  : wavesum, 4 fp32
    __shared__ __align__(16) unsigned char smem[2 * 16384 + 4096 + 512 + 16];
    unsigned char* wbuf = smem;
    float* w2s    = (float*)(smem + 32768);
    int*   jrow   = (int*)(smem + 36864);
    float* wavesum = (float*)(smem + 37376);

    const int t    = threadIdx.x;
    const int wv   = t >> 6;        // wave 0..3
    const int l15  = t & 15;
    const int lg   = (t & 63) >> 4; // k-group 0..3
    const int row0 = blockIdx.x * TM;

    // ---- A fragments: x rows, direct global -> regs, bf16. Wave-constant for whole K loop.
    // lane layout (16x16x32 A): row = lane&15, k = (lane>>4)*8 + e
    bf16x8 afrag[2][2];
#pragma unroll
    for (int mt = 0; mt < 2; ++mt)
#pragma unroll
        for (int ks = 0; ks < 2; ++ks) {
            const float* p = x + (size_t)(row0 + wv * 32 + mt * 16 + l15) * DIM + ks * 32 + lg * 8;
            float4 a0 = *(const float4*)p;
            float4 a1 = *(const float4*)(p + 4);
            bf16x8 f = { f2bf(a0.x), f2bf(a0.y), f2bf(a0.z), f2bf(a0.w),
                         f2bf(a1.x), f2bf(a1.y), f2bf(a1.z), f2bf(a1.w) };
            afrag[mt][ks] = f;
        }

    // ---- stage all w2 (4 KB) ----
#pragma unroll
    for (int i = 0; i < K_CODES / 256; ++i) w2s[t + i * 256] = w2g[t + i * 256];

    // ---- stage W chunk 0 into buf0 (swizzled bf16) ----
    float4 sa[4], sb[4];
#pragma unroll
    for (int i = 0; i < 4; ++i) {
        int p = i * 256 + t;                       // 0..1023 = 32B groups of chunk
        const float* g = W + (size_t)p * 8;
        sa[i] = *(const float4*)g;
        sb[i] = *(const float4*)(g + 4);
    }
#pragma unroll
    for (int i = 0; i < 4; ++i) {
        int p = i * 256 + t, r = p >> 3, gx = p & 7;
        bf16x8 vv = { f2bf(sa[i].x), f2bf(sa[i].y), f2bf(sa[i].z), f2bf(sa[i].w),
                      f2bf(sb[i].x), f2bf(sb[i].y), f2bf(sb[i].z), f2bf(sb[i].w) };
        *(bf16x8*)(wbuf + r * 128 + ((gx * 16) ^ ((r & 7) << 4))) = vv;
    }

    float best[2][4];
    int   bidx[2][4];
#pragma unroll
    for (int mt = 0; mt < 2; ++mt)
#pragma unroll
        for (int j = 0; j < 4; ++j) { best[mt][j] = 3.4e38f; bidx[mt][j] = 0; }

    for (int c = 0; c < NCHUNK; ++c) {
        __syncthreads();   // staged chunk c is ready in buf[c&1]

        // issue next-chunk global loads early (hide under MFMA)
        if (c + 1 < NCHUNK) {
#pragma unroll
            for (int i = 0; i < 4; ++i) {
                int p = i * 256 + t;
                const float* g = W + (size_t)(c + 1) * TK * DIM + (size_t)p * 8;
                sa[i] = *(const float4*)g;
                sb[i] = *(const float4*)(g + 4);
            }
        }

        const unsigned char* wb = wbuf + (c & 1) * 16384;
#pragma unroll
        for (int nt = 0; nt < 8; ++nt) {
            // B frag (16x16x32): col = lane&15, k = (lane>>4)*8 + e ; row-major W, swizzled
            int r = nt * 16 + l15;
            int sw = (r & 7) << 4;
            bf16x8 b0 = *(const bf16x8*)(wb + r * 128 + (((lg << 4))      ^ sw));
            bf16x8 b1 = *(const bf16x8*)(wb + r * 128 + ((64 + (lg << 4)) ^ sw));
            f32x4 acc0 = {0.f, 0.f, 0.f, 0.f}, acc1 = {0.f, 0.f, 0.f, 0.f};
            acc0 = __builtin_amdgcn_mfma_f32_16x16x32_bf16(afrag[0][0], b0, acc0, 0, 0, 0);
            acc0 = __builtin_amdgcn_mfma_f32_16x16x32_bf16(afrag[0][1], b1, acc0, 0, 0, 0);
            acc1 = __builtin_amdgcn_mfma_f32_16x16x32_bf16(afrag[1][0], b0, acc1, 0, 0, 0);
            acc1 = __builtin_amdgcn_mfma_f32_16x16x32_bf16(afrag[1][1], b1, acc1, 0, 0, 0);

            int   kidx = c * TK + nt * 16 + l15;
            float w2v  = w2s[kidx];
            // C layout: col = lane&15 (this kidx), row = (lane>>4)*4 + j
#pragma unroll
            for (int j = 0; j < 4; ++j) {
                float s0 = fmaf(-2.f, acc0[j], w2v);
                if (s0 < best[0][j]) { best[0][j] = s0; bidx[0][j] = kidx; }
                float s1 = fmaf(-2.f, acc1[j], w2v);
                if (s1 < best[1][j]) { best[1][j] = s1; bidx[1][j] = kidx; }
            }
        }

        // write staged regs into the other buffer (read last at chunk c-1 -> safe)
        if (c + 1 < NCHUNK) {
            unsigned char* wn = wbuf + ((c + 1) & 1) * 16384;
#pragma unroll
            for (int i = 0; i < 4; ++i) {
                int p = i * 256 + t, r = p >> 3, gx = p & 7;
                bf16x8 vv = { f2bf(sa[i].x), f2bf(sa[i].y), f2bf(sa[i].z), f2bf(sa[i].w),
                              f2bf(sb[i].x), f2bf(sb[i].y), f2bf(sb[i].z), f2bf(sb[i].w) };
                *(bf16x8*)(wn + r * 128 + ((gx * 16) ^ ((r & 7) << 4))) = vv;
            }
        }
    }

    // ---- cross-lane argmin reduce via LDS (reuse W buffers) ----
    __syncthreads();
    float* reds = (float*)smem;            // [128][16]
    int*   redi = (int*)(smem + 8192);     // [128][16]
#pragma unroll
    for (int mt = 0; mt < 2; ++mt)
#pragma unroll
        for (int j = 0; j < 4; ++j) {
            int r = wv * 32 + mt * 16 + lg * 4 + j;
            reds[r * 16 + l15] = best[mt][j];
            redi[r * 16 + l15] = bidx[mt][j];
        }
    __syncthreads();
    if (t < TM) {
        float b  = reds[t * 16];
        int   bi = redi[t * 16];
#pragma unroll
        for (int q = 1; q < 16; ++q) {
            float s  = reds[t * 16 + q];
            int   k2 = redi[t * 16 + q];
            if (s < b || (s == b && k2 < bi)) { b = s; bi = k2; }
        }
        jrow[t] = bi;
    }
    __syncthreads();

    // ---- epilogue: gather W[j] (exact fp32), write out, fused loss partial ----
    float psum = 0.f;
#pragma unroll
    for (int i = 0; i < 8; ++i) {
        int idx = t + i * 256;
        int r = idx >> 4;
        int cc = idx & 15;
        int j = jrow[r];
        float4 wvv = *(const float4*)(W + (size_t)j * DIM + cc * 4);
        *(float4*)(out + (size_t)(row0 + r) * DIM + cc * 4) = wvv;
        float4 xv = *(const float4*)(x + (size_t)(row0 + r) * DIM + cc * 4);
        float dx = xv.x - wvv.x, dy = xv.y - wvv.y;
        float dz = xv.z - wvv.z, dw = xv.w - wvv.w;
        psum += dx * dx + dy * dy + dz * dz + dw * dw;
    }
#pragma unroll
    for (int off = 32; off; off >>= 1) psum += __shfl_down(psum, off);
    if ((t & 63) == 0) wavesum[t >> 6] = psum;
    __syncthreads();
    if (t == 0) blocksum[blockIdx.x] = wavesum[0] + wavesum[1] + wavesum[2] + wavesum[3];
}

// ---------------- deterministic finish ----------------
__global__ __launch_bounds__(256) void finish_kernel(const float* __restrict__ bs,
                                                     float* __restrict__ out) {
    __shared__ float wavesum[4];
    int t = threadIdx.x;
    float s = 0.f;
    for (int i = t; i < N_TOK / TM; i += 256) s += bs[i];
#pragma unroll
    for (int off = 32; off; off >>= 1) s += __shfl_down(s, off);
    if ((t & 63) == 0) wavesum[t >> 6] = s;
    __syncthreads();
    if (t == 0)
        out[(size_t)N_TOK * DIM] = (wavesum[0] + wavesum[1] + wavesum[2] + wavesum[3]) *
                                   ((1.0f + ALPHA) / (float)N_TOK);
}

extern "C" void kernel_launch(void* const* d_in, const int* in_sizes, int n_in,
                              void* d_out, int out_size, void* d_ws, size_t ws_size,
                              hipStream_t stream) {
    const float* x = (const float*)d_in[0];
    const float* W = (const float*)d_in[1];
    float* out = (float*)d_out;
    float* ws  = (float*)d_ws;

    float* blocksum = ws;          // 1024 floats
    float* w2       = ws + 1024;   // 1024 floats

    w2_kernel<<<K_CODES / 256, 256, 0, stream>>>(W, w2);
    vq_kernel<<<N_TOK / TM, 256, 0, stream>>>(x, W, w2, out, blocksum);
    finish_kernel<<<1, 256, 0, stream>>>(blocksum, out);
}